// Round 1
// baseline (244.723 us; speedup 1.0000x reference)
//
#include <hip/hip_runtime.h>
#include <hip/hip_bf16.h>

// EdgeDetourHead: B=2, N=512, E=128, H=256, IN=3E+1=385
// out[b,i,j] = sym(MLP([h_i, h_j, |h_i-h_j|, e_ij]))
//
// Decomposition:
//   h1 = relu( PA[i] + PB[j] + |h_i-h_j|@W1c + e_ij*w1d + b1 )   (b1 folded into PA)
//   h2 = relu( h1@W2 + b2 )
//   p  = h2@W3 + b3 ; out = 0.5*(p+p^T) with zero diag
// PA/PB per-node in fp32 (exact); the two pairwise GEMMs in bf16 MFMA 32x32x16.

#define BN 512
#define EE 128
#define HH 256

typedef __attribute__((ext_vector_type(8)))  short short8;
typedef __attribute__((ext_vector_type(16))) float f32x16;
typedef __attribute__((ext_vector_type(4)))  float f32x4;

static __device__ __forceinline__ unsigned short f2bf(float f) {
    union { float f; unsigned u; } v; v.f = f;
    unsigned r = v.u + 0x7fff + ((v.u >> 16) & 1);   // RNE
    return (unsigned short)(r >> 16);
}
static __device__ __forceinline__ float bf2f(unsigned short s) {
    union { unsigned u; float f; } v; v.u = ((unsigned)s) << 16;
    return v.f;
}
static __device__ __forceinline__ f32x16 zero16() {
    f32x16 v;
    #pragma unroll
    for (int i = 0; i < 16; ++i) v[i] = 0.f;
    return v;
}

// ---------------- kernel 0: pack W1c / W2 into MFMA B-fragment order ----------------
// B-frag layout for v_mfma_f32_32x32x16_bf16: lane l holds B[k=(l>>5)*8+t][n=l&31],
// t=0..7. Packed index: ((kb*8+nb)*64 + l)*8 + t  -> one dwordx4 per lane, coalesced.
__global__ void pack_weights(const float* __restrict__ W1, const float* __restrict__ W2,
                             unsigned short* __restrict__ w1c_p, unsigned short* __restrict__ w2_p) {
    int idx = blockIdx.x * 256 + threadIdx.x;      // 0..65535
    if (idx < 32768) {                             // W1c: kb 0..7
        int t = idx & 7, l = (idx >> 3) & 63, nb = (idx >> 9) & 7, kb = idx >> 12;
        int k = kb * 16 + (l >> 5) * 8 + t;
        int n = nb * 32 + (l & 31);
        w1c_p[idx] = f2bf(W1[(256 + k) * HH + n]);
    }
    if (idx < 65536) {                             // W2: kb 0..15
        int t = idx & 7, l = (idx >> 3) & 63, nb = (idx >> 9) & 7, kb = idx >> 12;
        int k = kb * 16 + (l >> 5) * 8 + t;
        int n = nb * 32 + (l & 31);
        w2_p[idx] = f2bf(W2[k * HH + n]);
    }
}

// ---------------- kernel 1: per-node PA = h@W1a + b1, PB = h@W1b (fp32) ----------------
__global__ void precompute_pab(const float* __restrict__ node, const float* __restrict__ W1,
                               const float* __restrict__ b1,
                               float* __restrict__ PA, float* __restrict__ PB) {
    int bi = blockIdx.x;             // b*512 + i
    int h = threadIdx.x;             // 0..255
    const float* nd = node + (size_t)bi * EE;
    float sa = b1[h], sb = 0.f;
    #pragma unroll 4
    for (int e = 0; e < EE; ++e) {
        float x = nd[e];
        sa += x * W1[e * HH + h];
        sb += x * W1[(EE + e) * HH + h];
    }
    PA[bi * HH + h] = sa;
    PB[bi * HH + h] = sb;
}

// ---------------- kernel 2: fused main ----------------
// One WG = one (b, i) x 64 consecutive j.  4 waves; wave w owns h-cols [w*64, w*64+64).
// LDS row pads: D stride 136 shorts (272B = 17*16B, odd), h1 stride 264 (528B = 33*16B, odd)
// -> ds_read_b128 fragments spread across bank-quads.
__global__ __launch_bounds__(256, 3) void edge_main(
    const float* __restrict__ node, const float* __restrict__ euclid,
    const float* __restrict__ W1, const float* __restrict__ b2v,
    const float* __restrict__ W3, const float* __restrict__ b3,
    const float* __restrict__ PA, const float* __restrict__ PB,
    const unsigned short* __restrict__ w1c_p, const unsigned short* __restrict__ w2_p,
    float* __restrict__ out)
{
    __shared__ __align__(16) unsigned short lds_D[64 * 136];   // 17408 B (reused as pred partials)
    __shared__ __align__(16) unsigned short lds_h1[64 * 264];  // 33792 B (h1, then h2; row0 overlays hi)
    __shared__ float lds_e[64];

    const int jt = blockIdx.x, i = blockIdx.y, b = blockIdx.z;
    const int jbase = jt * 64;
    const int tid = threadIdx.x;
    const int wave = tid >> 6, lane = tid & 63;
    const int m0 = lane & 31, kq = (lane >> 5) * 8;

    float* hi_f = (float*)lds_h1;  // 128 floats, dead after D-build

    // stage h_i and euclid row
    if (tid < 32)
        ((f32x4*)hi_f)[tid] = ((const f32x4*)(node + ((size_t)b * BN + i) * EE))[tid];
    if (tid < 64)
        lds_e[tid] = euclid[((size_t)b * BN + i) * BN + jbase + tid];
    __syncthreads();

    // build D = |h_i - h_j| in bf16: 64 rows x 128 cols, 32 elems per thread
    {
        int row = tid >> 2, q = tid & 3;
        const f32x4* nj = (const f32x4*)(node + ((size_t)b * BN + jbase + row) * EE);
        const f32x4* hv = (const f32x4*)hi_f;
        unsigned short* dst = &lds_D[row * 136 + q * 32];
        #pragma unroll
        for (int k = 0; k < 4; ++k) {
            f32x4 a0 = nj[q * 8 + k * 2 + 0];
            f32x4 h0 = hv[q * 8 + k * 2 + 0];
            f32x4 a1 = nj[q * 8 + k * 2 + 1];
            f32x4 h1 = hv[q * 8 + k * 2 + 1];
            short8 pk;
            #pragma unroll
            for (int u = 0; u < 4; ++u) {
                pk[u]     = (short)f2bf(fabsf(a0[u] - h0[u]));
                pk[4 + u] = (short)f2bf(fabsf(a1[u] - h1[u]));
            }
            *(short8*)(dst + k * 8) = pk;
        }
    }
    __syncthreads();

    // ---- layer 1: C1[64 x 64strip] = D @ W1c ----
    f32x16 acc00 = zero16(), acc01 = zero16(), acc10 = zero16(), acc11 = zero16();
    {
        const short8* bp = (const short8*)w1c_p;
        #pragma unroll
        for (int kb = 0; kb < 8; ++kb) {
            short8 a0 = *(const short8*)&lds_D[m0 * 136 + kb * 16 + kq];
            short8 a1 = *(const short8*)&lds_D[(m0 + 32) * 136 + kb * 16 + kq];
            short8 b0 = bp[(kb * 8 + wave * 2 + 0) * 64 + lane];
            short8 b1 = bp[(kb * 8 + wave * 2 + 1) * 64 + lane];
            acc00 = __builtin_amdgcn_mfma_f32_32x32x16_bf16(a0, b0, acc00, 0, 0, 0);
            acc01 = __builtin_amdgcn_mfma_f32_32x32x16_bf16(a0, b1, acc01, 0, 0, 0);
            acc10 = __builtin_amdgcn_mfma_f32_32x32x16_bf16(a1, b0, acc10, 0, 0, 0);
            acc11 = __builtin_amdgcn_mfma_f32_32x32x16_bf16(a1, b1, acc11, 0, 0, 0);
        }
    }

    // epilogue 1: h1 = relu(C1 + PA[i] + PB[j] + e*w1d)  -> lds_h1 (bf16)
    {
        const float* paRow  = PA + ((size_t)b * BN + i) * HH;
        const float* w1d    = W1 + 384 * HH;
        const float* pbBase = PB + ((size_t)b * BN + jbase) * HH;
        auto epi = [&](const f32x16& a, int mt, int nt) {
            int col = wave * 64 + nt * 32 + (lane & 31);
            float pac = paRow[col], wdc = w1d[col];
            #pragma unroll
            for (int r = 0; r < 16; ++r) {
                int row = mt * 32 + (r & 3) + 8 * (r >> 2) + 4 * (lane >> 5);
                float v = a[r] + pac + pbBase[row * HH + col] + lds_e[row] * wdc;
                v = v > 0.f ? v : 0.f;
                lds_h1[row * 264 + col] = f2bf(v);
            }
        };
        epi(acc00, 0, 0); epi(acc01, 0, 1); epi(acc10, 1, 0); epi(acc11, 1, 1);
    }
    __syncthreads();

    // ---- layer 2: C2[64 x 64strip] = h1 @ W2 ----
    f32x16 c00 = zero16(), c01 = zero16(), c10 = zero16(), c11 = zero16();
    {
        const short8* bp = (const short8*)w2_p;
        #pragma unroll
        for (int kb = 0; kb < 16; ++kb) {
            short8 a0 = *(const short8*)&lds_h1[m0 * 264 + kb * 16 + kq];
            short8 a1 = *(const short8*)&lds_h1[(m0 + 32) * 264 + kb * 16 + kq];
            short8 b0 = bp[(kb * 8 + wave * 2 + 0) * 64 + lane];
            short8 b1 = bp[(kb * 8 + wave * 2 + 1) * 64 + lane];
            c00 = __builtin_amdgcn_mfma_f32_32x32x16_bf16(a0, b0, c00, 0, 0, 0);
            c01 = __builtin_amdgcn_mfma_f32_32x32x16_bf16(a0, b1, c01, 0, 0, 0);
            c10 = __builtin_amdgcn_mfma_f32_32x32x16_bf16(a1, b0, c10, 0, 0, 0);
            c11 = __builtin_amdgcn_mfma_f32_32x32x16_bf16(a1, b1, c11, 0, 0, 0);
        }
    }
    __syncthreads();   // all h1 reads complete before overwrite

    // epilogue 2: h2 = relu(C2 + b2) -> lds_h1 (bf16, same layout)
    {
        auto epi = [&](const f32x16& a, int mt, int nt) {
            int col = wave * 64 + nt * 32 + (lane & 31);
            float b2c = b2v[col];
            #pragma unroll
            for (int r = 0; r < 16; ++r) {
                int row = mt * 32 + (r & 3) + 8 * (r >> 2) + 4 * (lane >> 5);
                float v = a[r] + b2c;
                v = v > 0.f ? v : 0.f;
                lds_h1[row * 264 + col] = f2bf(v);
            }
        };
        epi(c00, 0, 0); epi(c01, 0, 1); epi(c10, 1, 0); epi(c11, 1, 1);
    }
    __syncthreads();

    // ---- layer 3: p[j] = h2[j,:] @ W3 + b3 (fp32, split-K by 4 threads/row) ----
    {
        int r = tid & 63, part = tid >> 6;
        int c0 = part * 64;
        float s = 0.f;
        #pragma unroll
        for (int k = 0; k < 8; ++k) {
            short8 h8 = *(const short8*)&lds_h1[r * 264 + c0 + k * 8];
            #pragma unroll
            for (int u = 0; u < 8; ++u)
                s += bf2f((unsigned short)h8[u]) * W3[c0 + k * 8 + u];
        }
        ((float*)lds_D)[part * 64 + r] = s;   // D buffer dead -> partials
    }
    __syncthreads();
    if (tid < 64) {
        const float* pp = (const float*)lds_D;
        float v = pp[tid] + pp[64 + tid] + pp[128 + tid] + pp[192 + tid] + b3[0];
        out[((size_t)b * BN + i) * BN + jbase + tid] = v;
    }
}

// ---------------- kernel 3: in-place symmetrize + zero diagonal ----------------
__global__ void symmetrize(float* __restrict__ out) {
    int b = blockIdx.z, ti = blockIdx.y, tj = blockIdx.x;
    if (tj < ti) return;                       // upper-triangle tiles only
    int i = ti * 32 + threadIdx.y, j = tj * 32 + threadIdx.x;
    float* p = out + (size_t)b * BN * BN;
    if (i == j) { p[(size_t)i * BN + j] = 0.f; return; }
    if (j < i) return;                         // lower half of diagonal tiles
    float a = p[(size_t)i * BN + j];
    float c = p[(size_t)j * BN + i];
    float v = 0.5f * (a + c);
    p[(size_t)i * BN + j] = v;
    p[(size_t)j * BN + i] = v;
}

extern "C" void kernel_launch(void* const* d_in, const int* in_sizes, int n_in,
                              void* d_out, int out_size, void* d_ws, size_t ws_size,
                              hipStream_t stream) {
    const float* node   = (const float*)d_in[0];
    // d_in[1] = problems (unused; euclid provided)
    const float* euclid = (const float*)d_in[2];
    const float* W1     = (const float*)d_in[3];
    const float* b1     = (const float*)d_in[4];
    const float* W2     = (const float*)d_in[5];
    const float* b2     = (const float*)d_in[6];
    const float* W3     = (const float*)d_in[7];
    const float* b3     = (const float*)d_in[8];
    float* out = (float*)d_out;

    char* ws = (char*)d_ws;
    float* PA = (float*)ws;                                   // 1 MB
    float* PB = (float*)(ws + (1u << 20));                    // 1 MB
    unsigned short* w1c_p = (unsigned short*)(ws + (2u << 20));            // 64 KB
    unsigned short* w2_p  = (unsigned short*)(ws + (2u << 20) + 65536);    // 128 KB

    pack_weights<<<256, 256, 0, stream>>>(W1, W2, w1c_p, w2_p);
    precompute_pab<<<BN * 2, 256, 0, stream>>>(node, W1, b1, PA, PB);
    edge_main<<<dim3(BN / 64, BN, 2), 256, 0, stream>>>(
        node, euclid, W1, b2, W3, b3, PA, PB, w1c_p, w2_p, out);
    symmetrize<<<dim3(BN / 32, BN / 32, 2), dim3(32, 32), 0, stream>>>(out);
}